// Round 1
// baseline (802.727 us; speedup 1.0000x reference)
//
#include <hip/hip_runtime.h>

#define TOK 4096
#define HD 1024
#define ID 4096
#define NE 8
#define BM 128
#define BN 128
#define BK 32
#define LSTR 40   // LDS row stride in shorts (80 B = 5*16B: aligned, odd*16 -> conflict-free b128 reads)

typedef __attribute__((ext_vector_type(4))) float f32x4;
typedef __attribute__((ext_vector_type(8))) __bf16 bf16x8;
typedef __attribute__((ext_vector_type(4))) unsigned short u16x4;
typedef __attribute__((ext_vector_type(8))) unsigned short u16x8;

__device__ __forceinline__ unsigned short f2bf(float f) {
  unsigned int u = __builtin_bit_cast(unsigned int, f);
  u += 0x7FFFu + ((u >> 16) & 1u);   // RNE
  return (unsigned short)(u >> 16);
}

__device__ __forceinline__ float gelu_tanh(float g) {
  // 0.5*g*(1+tanh(z)) == g*sigmoid(2z), z = sqrt(2/pi)*(g + 0.044715 g^3)
  float z = 0.7978845608028654f * (g + 0.044715f * g * g * g);
  float t = __expf(-2.0f * z);
  return g / (1.0f + t);
}

__global__ void init_k(int* __restrict__ meta) {
  if (threadIdx.x < 16) meta[threadIdx.x] = 0;
}

// one wave per token: fp32 logits (argmax must match numpy fp32), top1 via first-max
__global__ void router_k(const float* __restrict__ x, const float* __restrict__ gw,
                         float* __restrict__ logits, int* __restrict__ top1) {
  const int wid = threadIdx.x >> 6;
  const int lane = threadIdx.x & 63;
  const int t = blockIdx.x * 4 + wid;
  const float* xr = x + (size_t)t * HD;
  float acc[NE];
#pragma unroll
  for (int e = 0; e < NE; ++e) acc[e] = 0.0f;
#pragma unroll
  for (int c = 0; c < 4; ++c) {
    const int k = (c * 64 + lane) * 4;
    f32x4 xv = *(const f32x4*)(xr + k);
#pragma unroll
    for (int e = 0; e < NE; ++e) {
      f32x4 gv = *(const f32x4*)(gw + e * HD + k);
      acc[e] += xv[0] * gv[0] + xv[1] * gv[1] + xv[2] * gv[2] + xv[3] * gv[3];
    }
  }
#pragma unroll
  for (int off = 32; off > 0; off >>= 1) {
#pragma unroll
    for (int e = 0; e < NE; ++e) acc[e] += __shfl_xor(acc[e], off, 64);
  }
  if (lane == 0) {
    int best = 0; float bv = acc[0];
#pragma unroll
    for (int e = 1; e < NE; ++e) if (acc[e] > bv) { bv = acc[e]; best = e; }
    top1[t] = best;
#pragma unroll
    for (int e = 0; e < NE; ++e) logits[(size_t)t * NE + e] = acc[e];
  }
}

__global__ void hist_k(const int* __restrict__ top1, int* __restrict__ counts) {
  int t = blockIdx.x * 256 + threadIdx.x;
  atomicAdd(&counts[top1[t]], 1);
}

__global__ void offsets_k(const int* __restrict__ counts, int* __restrict__ offsets) {
  if (threadIdx.x == 0) {
    int s = 0;
    for (int e = 0; e < NE; ++e) { offsets[e] = s; s += counts[e]; }
  }
}

__global__ void scatter_k(const int* __restrict__ top1, const int* __restrict__ offsets,
                          int* __restrict__ counts2, int* __restrict__ perm) {
  int t = blockIdx.x * 256 + threadIdx.x;
  int e = top1[t];
  int slot = atomicAdd(&counts2[e], 1);
  perm[offsets[e] + slot] = t;
}

// hidden[p,:] = gelu(x_p @ wg[e]^T) * (x_p @ wu[e]^T), compacted rows p, bf16 out
__global__ __launch_bounds__(256) void gemm1_k(
    const float* __restrict__ x, const float* __restrict__ wg, const float* __restrict__ wu,
    const int* __restrict__ perm, const int* __restrict__ counts,
    const int* __restrict__ offsets, unsigned short* __restrict__ hidden) {
  const int e = blockIdx.z, mt = blockIdx.y, nt = blockIdx.x;
  const int ne = counts[e];
  if (mt * BM >= ne) return;
  const int off = offsets[e];

  __shared__ unsigned short la[BM * LSTR];
  __shared__ unsigned short lbg[BM * LSTR];
  __shared__ unsigned short lbu[BM * LSTR];

  const int tid = threadIdx.x;
  const int lane = tid & 63;
  const int wid = tid >> 6;
  const int wr = (wid >> 1) * 64;
  const int wc = (wid & 1) * 64;
  const int kc = tid & 7;        // 8 chunks of 4 fp32 per 32-elem row
  const int srow = tid >> 3;     // rows srow + 32*j

  int stok[4];
#pragma unroll
  for (int j = 0; j < 4; ++j) {
    int lr = mt * BM + srow + 32 * j;
    stok[j] = (lr < ne) ? perm[off + lr] : -1;
  }
  const float* bgb = wg + ((size_t)e * ID + (size_t)nt * BN) * HD;
  const float* bub = wu + ((size_t)e * ID + (size_t)nt * BN) * HD;

  f32x4 accg[4][4] = {};
  f32x4 accu[4][4] = {};

  for (int ks = 0; ks < HD / BK; ++ks) {
    const int k0 = ks * BK + kc * 4;
#pragma unroll
    for (int j = 0; j < 4; ++j) {
      const int r = srow + 32 * j;
      f32x4 av = {0.f, 0.f, 0.f, 0.f};
      if (stok[j] >= 0) av = *(const f32x4*)(x + (size_t)stok[j] * HD + k0);
      f32x4 gv = *(const f32x4*)(bgb + (size_t)r * HD + k0);
      f32x4 uv = *(const f32x4*)(bub + (size_t)r * HD + k0);
      const int wa = r * LSTR + kc * 4;
      u16x4 a4 = { f2bf(av[0]), f2bf(av[1]), f2bf(av[2]), f2bf(av[3]) };
      u16x4 g4 = { f2bf(gv[0]), f2bf(gv[1]), f2bf(gv[2]), f2bf(gv[3]) };
      u16x4 u4 = { f2bf(uv[0]), f2bf(uv[1]), f2bf(uv[2]), f2bf(uv[3]) };
      *(u16x4*)(la + wa) = a4;
      *(u16x4*)(lbg + wa) = g4;
      *(u16x4*)(lbu + wa) = u4;
    }
    __syncthreads();
    bf16x8 bgf[4], buf_[4];
#pragma unroll
    for (int ni = 0; ni < 4; ++ni) {
      const int adr = (wc + ni * 16 + (lane & 15)) * LSTR + (lane >> 4) * 8;
      bgf[ni] = *(const bf16x8*)(lbg + adr);
      buf_[ni] = *(const bf16x8*)(lbu + adr);
    }
#pragma unroll
    for (int mi = 0; mi < 4; ++mi) {
      const int adr = (wr + mi * 16 + (lane & 15)) * LSTR + (lane >> 4) * 8;
      bf16x8 af = *(const bf16x8*)(la + adr);
#pragma unroll
      for (int ni = 0; ni < 4; ++ni) {
        accg[mi][ni] = __builtin_amdgcn_mfma_f32_16x16x32_bf16(af, bgf[ni], accg[mi][ni], 0, 0, 0);
        accu[mi][ni] = __builtin_amdgcn_mfma_f32_16x16x32_bf16(af, buf_[ni], accu[mi][ni], 0, 0, 0);
      }
    }
    __syncthreads();
  }

  const int colb = nt * BN + wc + (lane & 15);
#pragma unroll
  for (int mi = 0; mi < 4; ++mi) {
#pragma unroll
    for (int j = 0; j < 4; ++j) {
      const int lrow = wr + mi * 16 + ((lane >> 4) << 2) + j;
      const int grow = mt * BM + lrow;
      if (grow < ne) {
        unsigned short* hrow = hidden + (size_t)(off + grow) * ID + colb;
#pragma unroll
        for (int ni = 0; ni < 4; ++ni) {
          float h = gelu_tanh(accg[mi][ni][j]) * accu[mi][ni][j];
          hrow[ni * 16] = f2bf(h);
        }
      }
    }
  }
}

// out[token,:] = hidden[p,:] @ wd[e]^T, scattered by perm
__global__ __launch_bounds__(256) void gemm2_k(
    const unsigned short* __restrict__ hidden, const float* __restrict__ wd,
    const int* __restrict__ perm, const int* __restrict__ counts,
    const int* __restrict__ offsets, float* __restrict__ out) {
  const int e = blockIdx.z, mt = blockIdx.y, nt = blockIdx.x;
  const int ne = counts[e];
  if (mt * BM >= ne) return;
  const int off = offsets[e];

  __shared__ unsigned short la[BM * LSTR];
  __shared__ unsigned short lb[BM * LSTR];

  const int tid = threadIdx.x;
  const int lane = tid & 63;
  const int wid = tid >> 6;
  const int wr = (wid >> 1) * 64;
  const int wc = (wid & 1) * 64;
  const int arow = tid >> 2, akc = tid & 3;  // A: 16B bf16 chunks, rows arow+64j
  const int brow = tid >> 3, bkc = tid & 7;  // B: fp32->bf16 8B chunks, rows brow+32j

  bool avalid[2];
#pragma unroll
  for (int j = 0; j < 2; ++j) avalid[j] = (mt * BM + arow + 64 * j) < ne;

  const float* bb = wd + ((size_t)e * HD + (size_t)nt * BN) * ID;

  f32x4 acc[4][4] = {};

  for (int ks = 0; ks < ID / BK; ++ks) {
#pragma unroll
    for (int j = 0; j < 2; ++j) {
      const int r = arow + 64 * j;
      u16x8 av = {0, 0, 0, 0, 0, 0, 0, 0};
      if (avalid[j])
        av = *(const u16x8*)(hidden + (size_t)(off + mt * BM + r) * ID + ks * BK + akc * 8);
      *(u16x8*)(la + r * LSTR + akc * 8) = av;
    }
#pragma unroll
    for (int j = 0; j < 4; ++j) {
      const int r = brow + 32 * j;
      f32x4 bv = *(const f32x4*)(bb + (size_t)r * ID + ks * BK + bkc * 4);
      u16x4 b4 = { f2bf(bv[0]), f2bf(bv[1]), f2bf(bv[2]), f2bf(bv[3]) };
      *(u16x4*)(lb + r * LSTR + bkc * 4) = b4;
    }
    __syncthreads();
    bf16x8 bf[4];
#pragma unroll
    for (int ni = 0; ni < 4; ++ni)
      bf[ni] = *(const bf16x8*)(lb + (wc + ni * 16 + (lane & 15)) * LSTR + (lane >> 4) * 8);
#pragma unroll
    for (int mi = 0; mi < 4; ++mi) {
      bf16x8 af = *(const bf16x8*)(la + (wr + mi * 16 + (lane & 15)) * LSTR + (lane >> 4) * 8);
#pragma unroll
      for (int ni = 0; ni < 4; ++ni)
        acc[mi][ni] = __builtin_amdgcn_mfma_f32_16x16x32_bf16(af, bf[ni], acc[mi][ni], 0, 0, 0);
    }
    __syncthreads();
  }

  const int colb = nt * BN + wc + (lane & 15);
#pragma unroll
  for (int mi = 0; mi < 4; ++mi) {
#pragma unroll
    for (int j = 0; j < 4; ++j) {
      const int lrow = wr + mi * 16 + ((lane >> 4) << 2) + j;
      const int grow = mt * BM + lrow;
      if (grow < ne) {
        const int t = perm[off + grow];
        float* orow = out + (size_t)t * HD + colb;
#pragma unroll
        for (int ni = 0; ni < 4; ++ni) orow[ni * 16] = acc[mi][ni][j];
      }
    }
  }
}

extern "C" void kernel_launch(void* const* d_in, const int* in_sizes, int n_in,
                              void* d_out, int out_size, void* d_ws, size_t ws_size,
                              hipStream_t stream) {
  const float* x  = (const float*)d_in[0];
  const float* gw = (const float*)d_in[1];
  const float* wg = (const float*)d_in[2];
  const float* wu = (const float*)d_in[3];
  const float* wd = (const float*)d_in[4];
  float* out = (float*)d_out;
  float* logits = out + (size_t)TOK * HD;

  unsigned short* hidden = (unsigned short*)d_ws;
  int* meta = (int*)((char*)d_ws + (size_t)TOK * ID * sizeof(unsigned short));
  int* counts  = meta;        // [8]
  int* counts2 = meta + 8;    // [8]
  int* offsets = meta + 16;   // [8]
  int* top1    = meta + 24;   // [TOK]
  int* perm    = meta + 24 + TOK;  // [TOK]

  init_k<<<1, 64, 0, stream>>>(meta);
  router_k<<<TOK / 4, 256, 0, stream>>>(x, gw, logits, top1);
  hist_k<<<TOK / 256, 256, 0, stream>>>(top1, counts);
  offsets_k<<<1, 64, 0, stream>>>(counts, offsets);
  scatter_k<<<TOK / 256, 256, 0, stream>>>(top1, offsets, counts2, perm);
  gemm1_k<<<dim3(ID / BN, TOK / BM, NE), 256, 0, stream>>>(x, wg, wu, perm, counts, offsets, hidden);
  gemm2_k<<<dim3(HD / BN, TOK / BM, NE), 256, 0, stream>>>(hidden, wd, perm, counts, offsets, out);
}

// Round 2
// 379.855 us; speedup vs baseline: 2.1132x; 2.1132x over previous
//
#include <hip/hip_runtime.h>

#define TOK 4096
#define HD 1024
#define ID 4096
#define NE 8
#define LS 72   // LDS row stride in shorts (144 B = 9*16B: 16B-aligned, odd multiple -> conflict-free)

typedef __attribute__((ext_vector_type(4))) float f32x4;
typedef __attribute__((ext_vector_type(8))) __bf16 bf16x8;
typedef __attribute__((ext_vector_type(4))) unsigned short u16x4;
typedef __attribute__((ext_vector_type(8))) unsigned short u16x8;

__device__ __forceinline__ unsigned short f2bf(float f) {
  unsigned int u = __builtin_bit_cast(unsigned int, f);
  u += 0x7FFFu + ((u >> 16) & 1u);   // RNE
  return (unsigned short)(u >> 16);
}

__device__ __forceinline__ u16x8 pack8(f32x4 a, f32x4 b) {
  u16x8 r = { f2bf(a[0]), f2bf(a[1]), f2bf(a[2]), f2bf(a[3]),
              f2bf(b[0]), f2bf(b[1]), f2bf(b[2]), f2bf(b[3]) };
  return r;
}

__device__ __forceinline__ float gelu_tanh(float g) {
  float z = 0.7978845608028654f * (g + 0.044715f * g * g * g);
  float t = __expf(-2.0f * z);
  return g / (1.0f + t);
}

__global__ void init_k(int* __restrict__ meta) {
  if (threadIdx.x < 16) meta[threadIdx.x] = 0;
}

// one wave per token: fp32 logits (argmax must match numpy fp32), top1 via first-max
__global__ void router_k(const float* __restrict__ x, const float* __restrict__ gw,
                         float* __restrict__ logits, int* __restrict__ top1) {
  const int wid = threadIdx.x >> 6;
  const int lane = threadIdx.x & 63;
  const int t = blockIdx.x * 4 + wid;
  const float* xr = x + (size_t)t * HD;
  float acc[NE];
#pragma unroll
  for (int e = 0; e < NE; ++e) acc[e] = 0.0f;
#pragma unroll
  for (int c = 0; c < 4; ++c) {
    const int k = (c * 64 + lane) * 4;
    f32x4 xv = *(const f32x4*)(xr + k);
#pragma unroll
    for (int e = 0; e < NE; ++e) {
      f32x4 gv = *(const f32x4*)(gw + e * HD + k);
      acc[e] += xv[0] * gv[0] + xv[1] * gv[1] + xv[2] * gv[2] + xv[3] * gv[3];
    }
  }
#pragma unroll
  for (int off = 32; off > 0; off >>= 1) {
#pragma unroll
    for (int e = 0; e < NE; ++e) acc[e] += __shfl_xor(acc[e], off, 64);
  }
  if (lane == 0) {
    int best = 0; float bv = acc[0];
#pragma unroll
    for (int e = 1; e < NE; ++e) if (acc[e] > bv) { bv = acc[e]; best = e; }
    top1[t] = best;
#pragma unroll
    for (int e = 0; e < NE; ++e) logits[(size_t)t * NE + e] = acc[e];
  }
}

__global__ void hist_k(const int* __restrict__ top1, int* __restrict__ counts) {
  int t = blockIdx.x * 256 + threadIdx.x;
  atomicAdd(&counts[top1[t]], 1);
}

__global__ void offsets_k(const int* __restrict__ counts, int* __restrict__ offsets) {
  if (threadIdx.x == 0) {
    int s = 0;
    for (int e = 0; e < NE; ++e) { offsets[e] = s; s += counts[e]; }
  }
}

__global__ void scatter_k(const int* __restrict__ top1, const int* __restrict__ offsets,
                          int* __restrict__ counts2, int* __restrict__ perm) {
  int t = blockIdx.x * 256 + threadIdx.x;
  int e = top1[t];
  int slot = atomicAdd(&counts2[e], 1);
  perm[offsets[e] + slot] = t;
}

// hidden[p,:] = gelu(x_p @ wg[e]^T) * (x_p @ wu[e]^T); 512 thr, 8 waves (2Mx4N), wave tile 64x32
__global__ __launch_bounds__(512, 2) void gemm1_k(
    const float* __restrict__ x, const float* __restrict__ wg, const float* __restrict__ wu,
    const int* __restrict__ perm, const int* __restrict__ counts,
    const int* __restrict__ offsets, unsigned short* __restrict__ hidden) {
  const int e = blockIdx.z, mt = blockIdx.y, nt = blockIdx.x;
  const int ne = counts[e];
  if (mt * 128 >= ne) return;
  const int off = offsets[e];

  __shared__ unsigned short la[128 * LS];
  __shared__ unsigned short lg[128 * LS];
  __shared__ unsigned short lu[128 * LS];

  const int tid = threadIdx.x;
  const int lane = tid & 63;
  const int wid = tid >> 6;
  const int wrow = (wid >> 2) * 64;
  const int wcol = (wid & 3) * 32;
  const int sc = tid & 7;        // 32B fp32 chunk within 64-elem row
  const int sr = tid >> 3;       // staging row 0..63 (+64 per round)

  const float* ap[2];
#pragma unroll
  for (int rd = 0; rd < 2; ++rd) {
    int lr = mt * 128 + sr + 64 * rd;
    int tok = (lr < ne) ? perm[off + lr] : perm[off];  // clamp; rows >= ne masked at store
    ap[rd] = x + (size_t)tok * HD + sc * 8;
  }
  const float* gp0 = wg + ((size_t)e * ID + nt * 128 + sr) * HD + sc * 8;
  const float* up0 = wu + ((size_t)e * ID + nt * 128 + sr) * HD + sc * 8;

  f32x4 accg[4][2] = {};
  f32x4 accu[4][2] = {};
  f32x4 ra[2][2], rg[2][2], ru[2][2];

#define LOADT(k0)                                                        \
  do {                                                                   \
    _Pragma("unroll") for (int rd = 0; rd < 2; ++rd) {                   \
      const float* a_ = ap[rd] + (k0);                                   \
      const float* g_ = gp0 + (size_t)rd * 64 * HD + (k0);               \
      const float* u_ = up0 + (size_t)rd * 64 * HD + (k0);               \
      ra[rd][0] = *(const f32x4*)a_; ra[rd][1] = *(const f32x4*)(a_ + 4);\
      rg[rd][0] = *(const f32x4*)g_; rg[rd][1] = *(const f32x4*)(g_ + 4);\
      ru[rd][0] = *(const f32x4*)u_; ru[rd][1] = *(const f32x4*)(u_ + 4);\
    }                                                                    \
  } while (0)

  LOADT(0);
  const int frow = lane & 15, fko = (lane >> 4) * 8;

  for (int ks = 0; ks < HD / 64; ++ks) {
#pragma unroll
    for (int rd = 0; rd < 2; ++rd) {
      const int wa = (sr + 64 * rd) * LS + sc * 8;
      *(u16x8*)(la + wa) = pack8(ra[rd][0], ra[rd][1]);
      *(u16x8*)(lg + wa) = pack8(rg[rd][0], rg[rd][1]);
      *(u16x8*)(lu + wa) = pack8(ru[rd][0], ru[rd][1]);
    }
    __syncthreads();
    if (ks + 1 < HD / 64) LOADT((ks + 1) * 64);  // T14: issue early, lands next iter
#pragma unroll
    for (int kk = 0; kk < 2; ++kk) {
      const int kb = kk * 32 + fko;
      bf16x8 a[4], g[2], u[2];
#pragma unroll
      for (int mi = 0; mi < 4; ++mi)
        a[mi] = *(const bf16x8*)(la + (wrow + mi * 16 + frow) * LS + kb);
#pragma unroll
      for (int ni = 0; ni < 2; ++ni) {
        g[ni] = *(const bf16x8*)(lg + (wcol + ni * 16 + frow) * LS + kb);
        u[ni] = *(const bf16x8*)(lu + (wcol + ni * 16 + frow) * LS + kb);
      }
#pragma unroll
      for (int mi = 0; mi < 4; ++mi)
#pragma unroll
        for (int ni = 0; ni < 2; ++ni) {
          accg[mi][ni] = __builtin_amdgcn_mfma_f32_16x16x32_bf16(a[mi], g[ni], accg[mi][ni], 0, 0, 0);
          accu[mi][ni] = __builtin_amdgcn_mfma_f32_16x16x32_bf16(a[mi], u[ni], accu[mi][ni], 0, 0, 0);
        }
    }
    __syncthreads();
  }
#undef LOADT

  const int colb = nt * 128 + wcol + (lane & 15);
#pragma unroll
  for (int mi = 0; mi < 4; ++mi) {
#pragma unroll
    for (int j = 0; j < 4; ++j) {
      const int grow = mt * 128 + wrow + mi * 16 + ((lane >> 4) << 2) + j;
      if (grow < ne) {
        unsigned short* hrow = hidden + (size_t)(off + grow) * ID + colb;
#pragma unroll
        for (int ni = 0; ni < 2; ++ni)
          hrow[ni * 16] = f2bf(gelu_tanh(accg[mi][ni][j]) * accu[mi][ni][j]);
      }
    }
  }
}

// out[token,:] = hidden[p,:] @ wd[e]^T; same 8-wave structure, K=4096
__global__ __launch_bounds__(512, 2) void gemm2_k(
    const unsigned short* __restrict__ hidden, const float* __restrict__ wd,
    const int* __restrict__ perm, const int* __restrict__ counts,
    const int* __restrict__ offsets, float* __restrict__ out) {
  const int e = blockIdx.z, mt = blockIdx.y, nt = blockIdx.x;
  const int ne = counts[e];
  if (mt * 128 >= ne) return;
  const int off = offsets[e];

  __shared__ unsigned short la[128 * LS];
  __shared__ unsigned short lb[128 * LS];

  const int tid = threadIdx.x;
  const int lane = tid & 63;
  const int wid = tid >> 6;
  const int wrow = (wid >> 2) * 64;
  const int wcol = (wid & 3) * 32;
  const int sc = tid & 7;
  const int sr = tid >> 3;

  const unsigned short* ap[2];
#pragma unroll
  for (int rd = 0; rd < 2; ++rd) {
    int lr = mt * 128 + sr + 64 * rd;
    int gr = off + ((lr < ne) ? lr : (ne - 1));  // clamp: stay inside hidden
    ap[rd] = hidden + (size_t)gr * ID + sc * 8;
  }
  const float* bp0 = wd + ((size_t)e * HD + nt * 128 + sr) * ID + sc * 8;

  f32x4 acc[4][2] = {};
  u16x8 rawa[2];
  f32x4 rb[2][2];

#define LOADT2(k0)                                                        \
  do {                                                                    \
    _Pragma("unroll") for (int rd = 0; rd < 2; ++rd) {                    \
      rawa[rd] = *(const u16x8*)(ap[rd] + (k0));                          \
      const float* b_ = bp0 + (size_t)rd * 64 * ID + (k0);                \
      rb[rd][0] = *(const f32x4*)b_; rb[rd][1] = *(const f32x4*)(b_ + 4); \
    }                                                                     \
  } while (0)

  LOADT2(0);
  const int frow = lane & 15, fko = (lane >> 4) * 8;

  for (int ks = 0; ks < ID / 64; ++ks) {
#pragma unroll
    for (int rd = 0; rd < 2; ++rd) {
      const int wa = (sr + 64 * rd) * LS + sc * 8;
      *(u16x8*)(la + wa) = rawa[rd];
      *(u16x8*)(lb + wa) = pack8(rb[rd][0], rb[rd][1]);
    }
    __syncthreads();
    if (ks + 1 < ID / 64) LOADT2((ks + 1) * 64);
#pragma unroll
    for (int kk = 0; kk < 2; ++kk) {
      const int kb = kk * 32 + fko;
      bf16x8 a[4], b[2];
#pragma unroll
      for (int mi = 0; mi < 4; ++mi)
        a[mi] = *(const bf16x8*)(la + (wrow + mi * 16 + frow) * LS + kb);
#pragma unroll
      for (int ni = 0; ni < 2; ++ni)
        b[ni] = *(const bf16x8*)(lb + (wcol + ni * 16 + frow) * LS + kb);
#pragma unroll
      for (int mi = 0; mi < 4; ++mi)
#pragma unroll
        for (int ni = 0; ni < 2; ++ni)
          acc[mi][ni] = __builtin_amdgcn_mfma_f32_16x16x32_bf16(a[mi], b[ni], acc[mi][ni], 0, 0, 0);
    }
    __syncthreads();
  }
#undef LOADT2

  const int colb = nt * 128 + wcol + (lane & 15);
#pragma unroll
  for (int mi = 0; mi < 4; ++mi) {
#pragma unroll
    for (int j = 0; j < 4; ++j) {
      const int grow = mt * 128 + wrow + mi * 16 + ((lane >> 4) << 2) + j;
      if (grow < ne) {
        const int t = perm[off + grow];
        float* orow = out + (size_t)t * HD + colb;
#pragma unroll
        for (int ni = 0; ni < 2; ++ni) orow[ni * 16] = acc[mi][ni][j];
      }
    }
  }
}

extern "C" void kernel_launch(void* const* d_in, const int* in_sizes, int n_in,
                              void* d_out, int out_size, void* d_ws, size_t ws_size,
                              hipStream_t stream) {
  const float* x  = (const float*)d_in[0];
  const float* gw = (const float*)d_in[1];
  const float* wg = (const float*)d_in[2];
  const float* wu = (const float*)d_in[3];
  const float* wd = (const float*)d_in[4];
  float* out = (float*)d_out;
  float* logits = out + (size_t)TOK * HD;

  unsigned short* hidden = (unsigned short*)d_ws;
  int* meta = (int*)((char*)d_ws + (size_t)TOK * ID * sizeof(unsigned short));
  int* counts  = meta;        // [8]
  int* counts2 = meta + 8;    // [8]
  int* offsets = meta + 16;   // [8]
  int* top1    = meta + 24;   // [TOK]
  int* perm    = meta + 24 + TOK;  // [TOK]

  init_k<<<1, 64, 0, stream>>>(meta);
  router_k<<<TOK / 4, 256, 0, stream>>>(x, gw, logits, top1);
  hist_k<<<TOK / 256, 256, 0, stream>>>(top1, counts);
  offsets_k<<<1, 64, 0, stream>>>(counts, offsets);
  scatter_k<<<TOK / 256, 256, 0, stream>>>(top1, offsets, counts2, perm);
  gemm1_k<<<dim3(ID / 128, TOK / 128, NE), 512, 0, stream>>>(x, wg, wu, perm, counts, offsets, hidden);
  gemm2_k<<<dim3(HD / 128, TOK / 128, NE), 512, 0, stream>>>(hidden, wd, perm, counts, offsets, out);
}

// Round 3
// 364.664 us; speedup vs baseline: 2.2013x; 1.0417x over previous
//
#include <hip/hip_runtime.h>

#define TOK 4096
#define HD 1024
#define ID 4096
#define NE 8
#define LS 72   // LDS row stride in shorts (144 B = 9*16B: 16B-aligned, odd multiple -> conflict-free b128 reads)

typedef __attribute__((ext_vector_type(4))) float f32x4;
typedef __attribute__((ext_vector_type(8))) __bf16 bf16x8;
typedef __attribute__((ext_vector_type(4))) unsigned short u16x4;
typedef __attribute__((ext_vector_type(8))) unsigned short u16x8;

// compiler emits v_cvt_pk_bf16_f32 (RNE) for scalar casts -- do NOT hand-roll (m240)
__device__ __forceinline__ bf16x8 pack8(f32x4 a, f32x4 b) {
  bf16x8 r;
#pragma unroll
  for (int i = 0; i < 4; ++i) { r[i] = (__bf16)a[i]; r[i + 4] = (__bf16)b[i]; }
  return r;
}

__device__ __forceinline__ float gelu_tanh(float g) {
  float z = 0.7978845608028654f * (g + 0.044715f * g * g * g);
  float t = __expf(-2.0f * z);
  return g / (1.0f + t);
}

// barrier that does NOT drain vmcnt: LDS ordering via lgkmcnt(0), global prefetch stays in flight
__device__ __forceinline__ void bar_lgkm() {
  asm volatile("s_waitcnt lgkmcnt(0)" ::: "memory");
  __builtin_amdgcn_s_barrier();
}

__global__ void init_k(int* __restrict__ meta) {
  if (threadIdx.x < 16) meta[threadIdx.x] = 0;
}

// one wave per token: fp32 logits (argmax must match numpy fp32), top1 via first-max
__global__ void router_k(const float* __restrict__ x, const float* __restrict__ gw,
                         float* __restrict__ logits, int* __restrict__ top1) {
  const int wid = threadIdx.x >> 6;
  const int lane = threadIdx.x & 63;
  const int t = blockIdx.x * 4 + wid;
  const float* xr = x + (size_t)t * HD;
  float acc[NE];
#pragma unroll
  for (int e = 0; e < NE; ++e) acc[e] = 0.0f;
#pragma unroll
  for (int c = 0; c < 4; ++c) {
    const int k = (c * 64 + lane) * 4;
    f32x4 xv = *(const f32x4*)(xr + k);
#pragma unroll
    for (int e = 0; e < NE; ++e) {
      f32x4 gv = *(const f32x4*)(gw + e * HD + k);
      acc[e] += xv[0] * gv[0] + xv[1] * gv[1] + xv[2] * gv[2] + xv[3] * gv[3];
    }
  }
#pragma unroll
  for (int off = 32; off > 0; off >>= 1) {
#pragma unroll
    for (int e = 0; e < NE; ++e) acc[e] += __shfl_xor(acc[e], off, 64);
  }
  if (lane == 0) {
    int best = 0; float bv = acc[0];
#pragma unroll
    for (int e = 1; e < NE; ++e) if (acc[e] > bv) { bv = acc[e]; best = e; }
    top1[t] = best;
#pragma unroll
    for (int e = 0; e < NE; ++e) logits[(size_t)t * NE + e] = acc[e];
  }
}

__global__ void hist_k(const int* __restrict__ top1, int* __restrict__ counts) {
  int t = blockIdx.x * 256 + threadIdx.x;
  atomicAdd(&counts[top1[t]], 1);
}

__global__ void offsets_k(const int* __restrict__ counts, int* __restrict__ offsets) {
  if (threadIdx.x == 0) {
    int s = 0;
    for (int e = 0; e < NE; ++e) { offsets[e] = s; s += counts[e]; }
  }
}

__global__ void scatter_k(const int* __restrict__ top1, const int* __restrict__ offsets,
                          int* __restrict__ counts2, int* __restrict__ perm) {
  int t = blockIdx.x * 256 + threadIdx.x;
  int e = top1[t];
  int slot = atomicAdd(&counts2[e], 1);
  perm[offsets[e] + slot] = t;
}

// hidden[p,:] = gelu(x_p @ wg[e]^T) * (x_p @ wu[e]^T); 512 thr, 8 waves (2Mx4N), wave tile 64x32
__global__ __launch_bounds__(512, 2) void gemm1_k(
    const float* __restrict__ x, const float* __restrict__ wg, const float* __restrict__ wu,
    const int* __restrict__ perm, const int* __restrict__ counts,
    const int* __restrict__ offsets, unsigned short* __restrict__ hidden) {
  const int e = blockIdx.z, mt = blockIdx.y, nt = blockIdx.x;
  const int ne = counts[e];
  if (mt * 128 >= ne) return;
  const int off = offsets[e];

  __shared__ unsigned short la[128 * LS];
  __shared__ unsigned short lg[128 * LS];
  __shared__ unsigned short lu[128 * LS];

  const int tid = threadIdx.x;
  const int lane = tid & 63;
  const int wid = tid >> 6;
  const int wrow = (wid >> 2) * 64;
  const int wcol = (wid & 3) * 32;
  const int sc = tid & 7;        // 32B fp32 chunk within 64-elem row
  const int sr = tid >> 3;       // staging row 0..63 (+64 per round)

  const float* ap[2];
#pragma unroll
  for (int rd = 0; rd < 2; ++rd) {
    int lr = mt * 128 + sr + 64 * rd;
    int tok = (lr < ne) ? perm[off + lr] : perm[off];  // clamp; rows >= ne masked at store
    ap[rd] = x + (size_t)tok * HD + sc * 8;
  }
  const float* gp0 = wg + ((size_t)e * ID + nt * 128 + sr) * HD + sc * 8;
  const float* up0 = wu + ((size_t)e * ID + nt * 128 + sr) * HD + sc * 8;

  f32x4 accg[4][2] = {};
  f32x4 accu[4][2] = {};
  f32x4 ra[2][2], rg[2][2], ru[2][2];

#define LOADT(k0)                                                        \
  do {                                                                   \
    _Pragma("unroll") for (int rd = 0; rd < 2; ++rd) {                   \
      const float* a_ = ap[rd] + (k0);                                   \
      const float* g_ = gp0 + (size_t)rd * 64 * HD + (k0);               \
      const float* u_ = up0 + (size_t)rd * 64 * HD + (k0);               \
      ra[rd][0] = *(const f32x4*)a_; ra[rd][1] = *(const f32x4*)(a_ + 4);\
      rg[rd][0] = *(const f32x4*)g_; rg[rd][1] = *(const f32x4*)(g_ + 4);\
      ru[rd][0] = *(const f32x4*)u_; ru[rd][1] = *(const f32x4*)(u_ + 4);\
    }                                                                    \
  } while (0)

  LOADT(0);
  const int frow = lane & 15, fko = (lane >> 4) * 8;

  for (int ks = 0; ks < HD / 64; ++ks) {
#pragma unroll
    for (int rd = 0; rd < 2; ++rd) {
      const int wa = (sr + 64 * rd) * LS + sc * 8;
      *(bf16x8*)(la + wa) = pack8(ra[rd][0], ra[rd][1]);
      *(bf16x8*)(lg + wa) = pack8(rg[rd][0], rg[rd][1]);
      *(bf16x8*)(lu + wa) = pack8(ru[rd][0], ru[rd][1]);
    }
    bar_lgkm();
    if (ks + 1 < HD / 64) LOADT((ks + 1) * 64);  // in flight across barriers (no vmcnt drain)
#pragma unroll
    for (int kk = 0; kk < 2; ++kk) {
      const int kb = kk * 32 + fko;
      bf16x8 a[4], g[2], u[2];
#pragma unroll
      for (int mi = 0; mi < 4; ++mi)
        a[mi] = *(const bf16x8*)(la + (wrow + mi * 16 + frow) * LS + kb);
#pragma unroll
      for (int ni = 0; ni < 2; ++ni) {
        g[ni] = *(const bf16x8*)(lg + (wcol + ni * 16 + frow) * LS + kb);
        u[ni] = *(const bf16x8*)(lu + (wcol + ni * 16 + frow) * LS + kb);
      }
#pragma unroll
      for (int mi = 0; mi < 4; ++mi)
#pragma unroll
        for (int ni = 0; ni < 2; ++ni) {
          accg[mi][ni] = __builtin_amdgcn_mfma_f32_16x16x32_bf16(a[mi], g[ni], accg[mi][ni], 0, 0, 0);
          accu[mi][ni] = __builtin_amdgcn_mfma_f32_16x16x32_bf16(a[mi], u[ni], accu[mi][ni], 0, 0, 0);
        }
    }
    bar_lgkm();
  }
#undef LOADT

  const int colb = nt * 128 + wcol + (lane & 15);
#pragma unroll
  for (int mi = 0; mi < 4; ++mi) {
#pragma unroll
    for (int j = 0; j < 4; ++j) {
      const int grow = mt * 128 + wrow + mi * 16 + ((lane >> 4) << 2) + j;
      if (grow < ne) {
        unsigned short* hrow = hidden + (size_t)(off + grow) * ID + colb;
#pragma unroll
        for (int ni = 0; ni < 2; ++ni) {
          __bf16 hb = (__bf16)(gelu_tanh(accg[mi][ni][j]) * accu[mi][ni][j]);
          hrow[ni * 16] = __builtin_bit_cast(unsigned short, hb);
        }
      }
    }
  }
}

// out[token,:] = hidden[p,:] @ wd[e]^T; same 8-wave structure, K=4096
__global__ __launch_bounds__(512, 2) void gemm2_k(
    const unsigned short* __restrict__ hidden, const float* __restrict__ wd,
    const int* __restrict__ perm, const int* __restrict__ counts,
    const int* __restrict__ offsets, float* __restrict__ out) {
  const int e = blockIdx.z, mt = blockIdx.y, nt = blockIdx.x;
  const int ne = counts[e];
  if (mt * 128 >= ne) return;
  const int off = offsets[e];

  __shared__ unsigned short la[128 * LS];
  __shared__ unsigned short lb[128 * LS];

  const int tid = threadIdx.x;
  const int lane = tid & 63;
  const int wid = tid >> 6;
  const int wrow = (wid >> 2) * 64;
  const int wcol = (wid & 3) * 32;
  const int sc = tid & 7;
  const int sr = tid >> 3;

  const unsigned short* ap[2];
#pragma unroll
  for (int rd = 0; rd < 2; ++rd) {
    int lr = mt * 128 + sr + 64 * rd;
    int gr = off + ((lr < ne) ? lr : (ne - 1));  // clamp: stay inside hidden
    ap[rd] = hidden + (size_t)gr * ID + sc * 8;
  }
  const float* bp0 = wd + ((size_t)e * HD + nt * 128 + sr) * ID + sc * 8;

  f32x4 acc[4][2] = {};
  u16x8 rawa[2];
  f32x4 rb[2][2];

#define LOADT2(k0)                                                        \
  do {                                                                    \
    _Pragma("unroll") for (int rd = 0; rd < 2; ++rd) {                    \
      rawa[rd] = *(const u16x8*)(ap[rd] + (k0));                          \
      const float* b_ = bp0 + (size_t)rd * 64 * ID + (k0);                \
      rb[rd][0] = *(const f32x4*)b_; rb[rd][1] = *(const f32x4*)(b_ + 4); \
    }                                                                     \
  } while (0)

  LOADT2(0);
  const int frow = lane & 15, fko = (lane >> 4) * 8;

  for (int ks = 0; ks < ID / 64; ++ks) {
#pragma unroll
    for (int rd = 0; rd < 2; ++rd) {
      const int wa = (sr + 64 * rd) * LS + sc * 8;
      *(u16x8*)(la + wa) = rawa[rd];
      *(bf16x8*)(lb + wa) = pack8(rb[rd][0], rb[rd][1]);
    }
    bar_lgkm();
    if (ks + 1 < ID / 64) LOADT2((ks + 1) * 64);
#pragma unroll
    for (int kk = 0; kk < 2; ++kk) {
      const int kb = kk * 32 + fko;
      bf16x8 a[4], b[2];
#pragma unroll
      for (int mi = 0; mi < 4; ++mi)
        a[mi] = *(const bf16x8*)(la + (wrow + mi * 16 + frow) * LS + kb);
#pragma unroll
      for (int ni = 0; ni < 2; ++ni)
        b[ni] = *(const bf16x8*)(lb + (wcol + ni * 16 + frow) * LS + kb);
#pragma unroll
      for (int mi = 0; mi < 4; ++mi)
#pragma unroll
        for (int ni = 0; ni < 2; ++ni)
          acc[mi][ni] = __builtin_amdgcn_mfma_f32_16x16x32_bf16(a[mi], b[ni], acc[mi][ni], 0, 0, 0);
    }
    bar_lgkm();
  }
#undef LOADT2

  const int colb = nt * 128 + wcol + (lane & 15);
#pragma unroll
  for (int mi = 0; mi < 4; ++mi) {
#pragma unroll
    for (int j = 0; j < 4; ++j) {
      const int grow = mt * 128 + wrow + mi * 16 + ((lane >> 4) << 2) + j;
      if (grow < ne) {
        const int t = perm[off + grow];
        float* orow = out + (size_t)t * HD + colb;
#pragma unroll
        for (int ni = 0; ni < 2; ++ni) orow[ni * 16] = acc[mi][ni][j];
      }
    }
  }
}

extern "C" void kernel_launch(void* const* d_in, const int* in_sizes, int n_in,
                              void* d_out, int out_size, void* d_ws, size_t ws_size,
                              hipStream_t stream) {
  const float* x  = (const float*)d_in[0];
  const float* gw = (const float*)d_in[1];
  const float* wg = (const float*)d_in[2];
  const float* wu = (const float*)d_in[3];
  const float* wd = (const float*)d_in[4];
  float* out = (float*)d_out;
  float* logits = out + (size_t)TOK * HD;

  unsigned short* hidden = (unsigned short*)d_ws;
  int* meta = (int*)((char*)d_ws + (size_t)TOK * ID * sizeof(unsigned short));
  int* counts  = meta;        // [8]
  int* counts2 = meta + 8;    // [8]
  int* offsets = meta + 16;   // [8]
  int* top1    = meta + 24;   // [TOK]
  int* perm    = meta + 24 + TOK;  // [TOK]

  init_k<<<1, 64, 0, stream>>>(meta);
  router_k<<<TOK / 4, 256, 0, stream>>>(x, gw, logits, top1);
  hist_k<<<TOK / 256, 256, 0, stream>>>(top1, counts);
  offsets_k<<<1, 64, 0, stream>>>(counts, offsets);
  scatter_k<<<TOK / 256, 256, 0, stream>>>(top1, offsets, counts2, perm);
  gemm1_k<<<dim3(ID / 128, TOK / 128, NE), 512, 0, stream>>>(x, wg, wu, perm, counts, offsets, hidden);
  gemm2_k<<<dim3(HD / 128, TOK / 128, NE), 512, 0, stream>>>(hidden, wd, perm, counts, offsets, out);
}